// Round 16
// baseline (298.053 us; speedup 1.0000x reference)
//
#include <hip/hip_runtime.h>
#include <cmath>

#define NTREE 256
#define MPT 511
#define NNODE (NTREE * MPT)   // 130816
#define HS 128

typedef __bf16 bf16x8 __attribute__((ext_vector_type(8)));
typedef float  f32x4  __attribute__((ext_vector_type(4)));

__device__ __forceinline__ float sigf(float x) {
  float e = __builtin_amdgcn_exp2f(x * -1.44269504f);
  return __builtin_amdgcn_rcpf(1.0f + e);
}
__device__ __forceinline__ float tanh_fast(float x) {
  float e = __builtin_amdgcn_exp2f(x * -2.88539008f);
  return __builtin_amdgcn_rcpf(1.0f + e) * 2.0f - 1.0f;
}
__device__ __forceinline__ f32x4 mm(bf16x8 a, bf16x8 b, f32x4 c) {
  return __builtin_amdgcn_mfma_f32_16x16x32_bf16(a, b, c, 0, 0, 0);
}
// XOR-swizzled LDS tile helpers (T2): row-major bf16, 16B chunk swizzle
__device__ __forceinline__ int swz(int row, int rb, int kb) { return row * rb + (kb ^ ((row & 7) << 4)); }
__device__ __forceinline__ void st8(char* s, int row, int rb, int chunk, bf16x8 v) {
  *reinterpret_cast<bf16x8*>(s + swz(row, rb, chunk * 16)) = v;
}
__device__ __forceinline__ bf16x8 ld8(const char* s, int row, int rb, int kb) {
  return *reinterpret_cast<const bf16x8*>(s + swz(row, rb, kb));
}
__device__ __forceinline__ bf16x8 g8(const __bf16* p) { return *reinterpret_cast<const bf16x8*>(p); }
__device__ __forceinline__ bf16x8 gx8(const float* p) {   // f32 row -> bf16x8
  float4 v0 = reinterpret_cast<const float4*>(p)[0];
  float4 v1 = reinterpret_cast<const float4*>(p)[1];
  bf16x8 o;
  o[0] = (__bf16)v0.x; o[1] = (__bf16)v0.y; o[2] = (__bf16)v0.z; o[3] = (__bf16)v0.w;
  o[4] = (__bf16)v1.x; o[5] = (__bf16)v1.y; o[6] = (__bf16)v1.z; o[7] = (__bf16)v1.w;
  return o;
}
__device__ __forceinline__ void stbf(char* s, int row, int rb, int kbyte, float v) {
  *reinterpret_cast<__bf16*>(s + row * rb + (kbyte ^ ((row & 7) << 4))) = (__bf16)v;
}

// ---------------------------------------------------------------------------
// BU bottom: one block = 16 t7-nodes + their 32 leaf children. 512 thr, 8
// waves, wave = 16-ch slice. Small LDS (24KB) -> multiple blocks/CU for TLP.
// Leaf htild/cred stay in LDS; t7 computed in-block; epilogue pushes t6.
// ---------------------------------------------------------------------------
__global__ void __launch_bounds__(512, 2)
bu_bottom(const float* __restrict__ Xf,
          const __bf16* __restrict__ W, const float* __restrict__ bp,
          const __bf16* __restrict__ Uf, const float* __restrict__ bf_,
          __bf16* __restrict__ h_bu, float* __restrict__ cws)
{
  __shared__ __align__(16) char sX8[32 * 256];   // leaf x, then h-bounce (8KB)
  __shared__ __align__(16) char sX7[16 * 256];   // t7 x, then h-bounce (4KB)
  __shared__ __align__(16) char sT [16 * 256];   // htild for t7 (4KB)
  __shared__ float sCr[16][128];                 // cred for t7 (8KB)

  const int tid = threadIdx.x, w = tid >> 6, l = tid & 63, lr = l & 15, lk = l >> 4;
  const int ch = w * 16 + lr;
  const int vb = blockIdx.x * 16;
  const int b  = vb >> 7;
  const int j7 = 127 + (vb & 127);                      // t=7 starts at 127 (odd)
  const size_t g7  = (size_t)b * MPT + j7;
  const size_t gLf = (size_t)b * MPT + 2 * j7 + 1;
  const size_t gp6 = (size_t)b * MPT + ((j7 - 1) >> 1);

  // ---- weights (streamed; TLP hides latency) ----
  bf16x8 Wb[8][3], Uff[4];
#pragma unroll
  for (int ks = 0; ks < 8; ++ks)
#pragma unroll
    for (int g2 = 0; g2 < 3; ++g2)
      Wb[ks][g2] = g8(W + (size_t)(g2 * 128 + ch) * 256 + ks * 32 + lk * 8);
#pragma unroll
  for (int ks = 0; ks < 4; ++ks) Uff[ks] = g8(Uf + (size_t)ch * HS + ks * 32 + lk * 8);

  // ---- stage leaf x (32 rows) + t7 x (16 rows) ----
  { int n = tid >> 4, e = tid & 15;
    st8(sX8, n, 256, e, gx8(Xf + (gLf + n) * HS + e * 8)); }
  if (tid < 256) { int n = tid >> 4, e = tid & 15;
    st8(sX7, n, 256, e, gx8(Xf + (g7 + n) * HS + e * 8)); }

  const float bia = bp[ch], boa = bp[ch + 128], bua = bp[ch + 256], bfa = bf_[ch];
  __syncthreads();

  // ================= leaf phase: M=32, K=128 =================
  f32x4 acc[3][2];
#pragma unroll
  for (int g2 = 0; g2 < 3; ++g2) { acc[g2][0] = 0.0f; acc[g2][1] = 0.0f; }
#pragma unroll
  for (int ks = 0; ks < 4; ++ks) {
    const int kb = ks * 64 + lk * 16;
    bf16x8 A0 = ld8(sX8, lr,      256, kb);
    bf16x8 A1 = ld8(sX8, 16 + lr, 256, kb);
#pragma unroll
    for (int g2 = 0; g2 < 3; ++g2) {
      acc[g2][0] = mm(A0, Wb[ks][g2], acc[g2][0]);
      acc[g2][1] = mm(A1, Wb[ks][g2], acc[g2][1]);
    }
  }
  float cnv[2][4], hnv[2][4];
#pragma unroll
  for (int mf = 0; mf < 2; ++mf)
#pragma unroll
    for (int j = 0; j < 4; ++j) {
      const int nrow = 16 * mf + lk * 4 + j;
      float cn = sigf(acc[0][mf][j] + bia) * tanh_fast(acc[2][mf][j] + bua);
      float hn = sigf(acc[1][mf][j] + boa) * tanh_fast(cn);
      cnv[mf][j] = cn; hnv[mf][j] = hn;
      h_bu[(gLf + nrow) * HS + ch] = (__bf16)hn;
    }
  __syncthreads();
#pragma unroll
  for (int mf = 0; mf < 2; ++mf)
#pragma unroll
    for (int j = 0; j < 4; ++j)
      stbf(sX8, 16 * mf + lk * 4 + j, 256, 2 * ch, hnv[mf][j]);
  __syncthreads();
  {
    f32x4 fa[2]; fa[0] = 0.0f; fa[1] = 0.0f;
#pragma unroll
    for (int ks = 0; ks < 4; ++ks) {
      const int kb = ks * 64 + lk * 16;
      fa[0] = mm(ld8(sX8, lr,      256, kb), Uff[ks], fa[0]);
      fa[1] = mm(ld8(sX8, 16 + lr, 256, kb), Uff[ks], fa[1]);
    }
#pragma unroll
    for (int mf = 0; mf < 2; ++mf)
#pragma unroll
      for (int p = 0; p < 2; ++p) {
        const int er = 16 * mf + lk * 4 + 2 * p;
        const int pr = er >> 1;                        // 0..15
        float f0 = sigf(fa[mf][2 * p]     + bfa) * cnv[mf][2 * p];
        float f1 = sigf(fa[mf][2 * p + 1] + bfa) * cnv[mf][2 * p + 1];
        sCr[pr][ch] = f0 + f1;
        stbf(sT, pr, 256, 2 * ch, hnv[mf][2 * p] + hnv[mf][2 * p + 1]);
      }
  }
  __syncthreads();

  // ================= t7 phase: M=16, K=256 ([x | htild]) =================
  f32x4 ac2[3];
#pragma unroll
  for (int g2 = 0; g2 < 3; ++g2) ac2[g2] = 0.0f;
#pragma unroll
  for (int ks = 0; ks < 8; ++ks) {
    const int kb = (ks & 3) * 64 + lk * 16;
    bf16x8 A0 = (ks < 4) ? ld8(sX7, lr, 256, kb) : ld8(sT, lr, 256, kb);
#pragma unroll
    for (int g2 = 0; g2 < 3; ++g2) ac2[g2] = mm(A0, Wb[ks][g2], ac2[g2]);
  }
  float cn2[4], hn2[4];
#pragma unroll
  for (int j = 0; j < 4; ++j) {
    const int nr = lk * 4 + j;
    float cn = sigf(ac2[0][j] + bia) * tanh_fast(ac2[2][j] + bua) + sCr[nr][ch];
    float hn = sigf(ac2[1][j] + boa) * tanh_fast(cn);
    cn2[j] = cn; hn2[j] = hn;
    h_bu[(g7 + nr) * HS + ch] = (__bf16)hn;
  }
  __syncthreads();
#pragma unroll
  for (int j = 0; j < 4; ++j)
    stbf(sX7, lk * 4 + j, 256, 2 * ch, hn2[j]);
  __syncthreads();
  {
    f32x4 fb = 0.0f;
#pragma unroll
    for (int ks = 0; ks < 4; ++ks)
      fb = mm(ld8(sX7, lr, 256, ks * 64 + lk * 16), Uff[ks], fb);
#pragma unroll
    for (int p = 0; p < 2; ++p) {
      const int er = lk * 4 + 2 * p;
      const size_t gp = gp6 + (er >> 1);               // 0..7
      float f0 = sigf(fb[2 * p]     + bfa) * cn2[2 * p];
      float f1 = sigf(fb[2 * p + 1] + bfa) * cn2[2 * p + 1];
      cws[gp * HS + ch] = f0 + f1;
      h_bu[gp * HS + ch] = (__bf16)(hn2[2 * p] + hn2[2 * p + 1]);
    }
  }
}

// ---------------------------------------------------------------------------
// TD bottom: one block = 16 t7-nodes + 32 leaf children. Small LDS (40KB).
// t7's h_td/fc stay in LDS; leaves reduce in-register to `part`.
// ---------------------------------------------------------------------------
__global__ void __launch_bounds__(512, 2)
td_bottom(const float* __restrict__ Xf,
          const __bf16* __restrict__ W, const float* __restrict__ bp,
          const __bf16* __restrict__ Uf, const float* __restrict__ bf_,
          const __bf16* __restrict__ h_bu, const __bf16* __restrict__ h_td,
          const float* __restrict__ cws, float* __restrict__ part)
{
  __shared__ __align__(16) char sA7[16 * 768];   // t7 [x | h_bu | h_td(par)] (12KB)
  __shared__ __align__(16) char sXH[32 * 512];   // leaves [x | h_bu] (16KB)
  __shared__ __align__(16) char sTd[16 * 256];   // h_td t7 (4KB)
  __shared__ float sFc[16][128];                 // fc t7 (8KB)

  const int tid = threadIdx.x, w = tid >> 6, l = tid & 63, lr = l & 15, lk = l >> 4;
  const int ch = w * 16 + lr;
  const int vb = blockIdx.x * 16;
  const int b  = vb >> 7;
  const int j7 = 127 + (vb & 127);
  const size_t g7  = (size_t)b * MPT + j7;
  const size_t gLf = (size_t)b * MPT + 2 * j7 + 1;
  const size_t gp6 = (size_t)b * MPT + ((j7 - 1) >> 1);

  // ---- weights (streamed) ----
  bf16x8 Wt[12][3], Uff[4];
#pragma unroll
  for (int ks = 0; ks < 12; ++ks)
#pragma unroll
    for (int g2 = 0; g2 < 3; ++g2)
      Wt[ks][g2] = g8(W + (size_t)(g2 * 128 + ch) * 384 + ks * 32 + lk * 8);
#pragma unroll
  for (int ks = 0; ks < 4; ++ks) Uff[ks] = g8(Uf + (size_t)ch * HS + ks * 32 + lk * 8);

  // ---- stage everything in one batch ----
  if (tid < 256) { int n = tid >> 4, e = tid & 15;   // t7 rows
    st8(sA7, n, 768, e,      gx8(Xf   + (g7 + n) * HS + e * 8));
    st8(sA7, n, 768, 16 + e, g8(h_bu + (g7 + n) * HS + e * 8));
    st8(sA7, n, 768, 32 + e, g8(h_td + (gp6 + (n >> 1)) * HS + e * 8)); }
  { int n = tid >> 4, e = tid & 15;                  // 32 leaf rows
    st8(sXH, n, 512, e,      gx8(Xf   + (gLf + n) * HS + e * 8));
    st8(sXH, n, 512, 16 + e, g8(h_bu + (gLf + n) * HS + e * 8)); }
  float cb[4];
#pragma unroll
  for (int j = 0; j < 4; ++j) {
    const int nr = lk * 4 + j;
    cb[j] = cws[(gp6 + (nr >> 1)) * HS + ch];
  }
  const float bia = bp[ch], boa = bp[ch + 128], bua = bp[ch + 256], bfa = bf_[ch];
  __syncthreads();

  // ================= t7 phase: M=16, K=384 =================
  f32x4 ac[3];
#pragma unroll
  for (int g2 = 0; g2 < 3; ++g2) ac[g2] = 0.0f;
#pragma unroll
  for (int ks = 0; ks < 12; ++ks) {
    const int kb = ks * 64 + lk * 16;
    bf16x8 A0 = ld8(sA7, lr, 768, kb);
#pragma unroll
    for (int g2 = 0; g2 < 3; ++g2) ac[g2] = mm(A0, Wt[ks][g2], ac[g2]);
  }
  float cn7[4];
#pragma unroll
  for (int j = 0; j < 4; ++j) {
    const int nr = lk * 4 + j;
    float cn = sigf(ac[0][j] + bia) * tanh_fast(ac[2][j] + bua) + cb[j];
    float hn = sigf(ac[1][j] + boa) * tanh_fast(cn);
    cn7[j] = cn;
    stbf(sTd, nr, 256, 2 * ch, hn);
  }
  __syncthreads();
  {
    f32x4 fa = 0.0f;
#pragma unroll
    for (int ks = 0; ks < 4; ++ks)
      fa = mm(ld8(sTd, lr, 256, ks * 64 + lk * 16), Uff[ks], fa);
#pragma unroll
    for (int j = 0; j < 4; ++j) {
      const int nr = lk * 4 + j;
      sFc[nr][ch] = sigf(fa[j] + bfa) * cn7[j];
    }
  }
  __syncthreads();

  // ================= leaf phase: M=32, K=384, LEAFOUT =================
  f32x4 a8[3][2];
#pragma unroll
  for (int g2 = 0; g2 < 3; ++g2) { a8[g2][0] = 0.0f; a8[g2][1] = 0.0f; }
#pragma unroll
  for (int ks = 0; ks < 12; ++ks) {
    bf16x8 A0, A1;
    if (ks < 8) {
      const int kb = ks * 64 + lk * 16;
      A0 = ld8(sXH, lr,      512, kb);
      A1 = ld8(sXH, 16 + lr, 512, kb);
    } else {
      const int kb = (ks - 8) * 64 + lk * 16;
      A0 = ld8(sTd, (lr >> 1),     256, kb);
      A1 = ld8(sTd, 8 + (lr >> 1), 256, kb);
    }
#pragma unroll
    for (int g2 = 0; g2 < 3; ++g2) {
      a8[g2][0] = mm(A0, Wt[ks][g2], a8[g2][0]);
      a8[g2][1] = mm(A1, Wt[ks][g2], a8[g2][1]);
    }
  }
  float psum = 0.0f;
#pragma unroll
  for (int mf = 0; mf < 2; ++mf)
#pragma unroll
    for (int j = 0; j < 4; ++j) {
      const int nrow = 16 * mf + lk * 4 + j;
      float cbase = sFc[nrow >> 1][ch];
      float cn = sigf(a8[0][mf][j] + bia) * tanh_fast(a8[2][mf][j] + bua) + cbase;
      float hn = sigf(a8[1][mf][j] + boa) * tanh_fast(cn);
      psum += hn;
    }
  float s = psum;
  s += __shfl_xor(s, 16);
  s += __shfl_xor(s, 32);
  if (lk == 0) part[(size_t)blockIdx.x * 128 + ch] = s;
}

// ---------------------------------------------------------------------------
// Mid-level kernel (round-9 structure, unchanged): 64 nodes/block, 4 waves.
// MODE: 1 = BU internal (K=256), 3 = TD (K=384). Always EPI.
// ---------------------------------------------------------------------------
template <int MODE>
__global__ void __launch_bounds__(256, 2)
level_big(int t,
          const float*  __restrict__ Xf,
          const __bf16* __restrict__ W,
          const float*  __restrict__ bp,
          const __bf16* __restrict__ Uf,
          const float*  __restrict__ bf_,
          __bf16* __restrict__ h_bu,
          __bf16* __restrict__ h_td,
          float*  __restrict__ cws)
{
  constexpr int KA = (MODE == 1) ? 256 : 384;
  constexpr int KS = KA / 32;
  constexpr int BK = (MODE == 3) ? 384 : 256;
  constexpr int RB = KA * 2;
  constexpr int HB = (MODE == 1) ? 256 : 512;

  __shared__ __align__(16) char sA[64 * RB];
  __shared__ int sG[64], sP[64];

  const int tid = threadIdx.x;
  const int w = tid >> 6, l = tid & 63, lr = l & 15, lk = l >> 4;

  if (tid < 64) {
    int v = blockIdx.x * 64 + tid;
    int b = v >> t;
    int j = (1 << t) - 1 + (v & ((1 << t) - 1));
    sG[tid] = b * MPT + j;
    sP[tid] = b * MPT + ((j - 1) >> 1);
  }
  __syncthreads();

#pragma unroll
  for (int it = 0; it < 4; ++it) {
    int idx = tid + it * 256, n = idx >> 4, e = idx & 15;
    st8(sA, n, RB, e, gx8(Xf + (size_t)sG[n] * HS + e * 8));
  }
#pragma unroll
  for (int it = 0; it < 4; ++it) {
    int idx = tid + it * 256, n = idx >> 4, e = idx & 15;
    st8(sA, n, RB, 16 + e, g8(h_bu + (size_t)sG[n] * HS + e * 8));
  }
  if constexpr (MODE == 3) {
#pragma unroll
    for (int it = 0; it < 4; ++it) {
      int idx = tid + it * 256, n = idx >> 4, e = idx & 15;
      st8(sA, n, RB, 32 + e, g8(h_td + (size_t)sP[n] * HS + e * 8));
    }
  }
  __syncthreads();

  float cb[2][4][4];
  float bia[2], boa[2], bua[2], bfa[2];
#pragma unroll
  for (int nf = 0; nf < 2; ++nf) {
    const int ch = w * 32 + nf * 16 + lr;
    bia[nf] = bp[ch]; boa[nf] = bp[ch + 128]; bua[nf] = bp[ch + 256];
    bfa[nf] = bf_[ch];
#pragma unroll
    for (int mf = 0; mf < 4; ++mf)
#pragma unroll
      for (int j = 0; j < 4; ++j) {
        const int nrow = 16 * mf + lk * 4 + j;
        const int src = (MODE == 1) ? sG[nrow] : sP[nrow];
        cb[nf][mf][j] = cws[(size_t)src * HS + ch];
      }
  }

  f32x4 acc[6][4];
#pragma unroll
  for (int p = 0; p < 6; ++p)
#pragma unroll
    for (int mf = 0; mf < 4; ++mf) acc[p][mf] = 0.0f;

  bf16x8 A0[4], A1[4], Bb[3][6];
  auto ldA = [&](int ks, bf16x8* Ad) {
#pragma unroll
    for (int mf = 0; mf < 4; ++mf) Ad[mf] = ld8(sA, mf * 16 + lr, RB, ks * 64 + lk * 16);
  };
  auto ldB = [&](int ks, int s) {
#pragma unroll
    for (int g2 = 0; g2 < 3; ++g2)
#pragma unroll
      for (int nf = 0; nf < 2; ++nf)
        Bb[s][g2 * 2 + nf] = g8(W + (size_t)(g2 * 128 + w * 32 + nf * 16 + lr) * BK + ks * 32 + lk * 8);
  };

  ldB(0, 0); ldA(0, A0); ldB(1, 1);
#pragma unroll
  for (int ks = 0; ks < KS; ++ks) {
    bf16x8* Ac = (ks & 1) ? A1 : A0;
    bf16x8* An = (ks & 1) ? A0 : A1;
    if (ks + 1 < KS) ldA(ks + 1, An);
    if (ks + 2 < KS) ldB(ks + 2, (ks + 2) % 3);
#pragma unroll
    for (int p = 0; p < 6; ++p)
#pragma unroll
      for (int mf = 0; mf < 4; ++mf) acc[p][mf] = mm(Ac[mf], Bb[ks % 3][p], acc[p][mf]);
  }

  bf16x8 Uff[8];
#pragma unroll
  for (int ks = 0; ks < 4; ++ks)
#pragma unroll
    for (int nf = 0; nf < 2; ++nf)
      Uff[ks * 2 + nf] = g8(Uf + (size_t)(w * 32 + nf * 16 + lr) * HS + ks * 32 + lk * 8);

  __bf16* hp = (MODE == 3) ? h_td : h_bu;
  float cnv[2][4][4], hnv[2][4][4];
#pragma unroll
  for (int nf = 0; nf < 2; ++nf) {
    const int ch = w * 32 + nf * 16 + lr;
#pragma unroll
    for (int mf = 0; mf < 4; ++mf)
#pragma unroll
      for (int j = 0; j < 4; ++j) {
        const int nrow = 16 * mf + lk * 4 + j;
        float cn = sigf(acc[nf][mf][j] + bia[nf]) * tanh_fast(acc[4 + nf][mf][j] + bua[nf]) + cb[nf][mf][j];
        float hn = sigf(acc[2 + nf][mf][j] + boa[nf]) * tanh_fast(cn);
        hp[(size_t)sG[nrow] * HS + ch] = (__bf16)hn;
        cnv[nf][mf][j] = cn; hnv[nf][mf][j] = hn;
      }
  }

  __syncthreads();
#pragma unroll
  for (int nf = 0; nf < 2; ++nf) {
    const int ch = w * 32 + nf * 16 + lr;
#pragma unroll
    for (int mf = 0; mf < 4; ++mf)
#pragma unroll
      for (int j = 0; j < 4; ++j)
        stbf(sA, 16 * mf + lk * 4 + j, RB, HB + 2 * ch, hnv[nf][mf][j]);
  }
  __syncthreads();
  f32x4 fa[4][2];
#pragma unroll
  for (int mf = 0; mf < 4; ++mf) { fa[mf][0] = 0.0f; fa[mf][1] = 0.0f; }
#pragma unroll
  for (int ks = 0; ks < 4; ++ks) {
    bf16x8 a0 = ld8(sA, lr,      RB, HB + ks * 64 + lk * 16);
    bf16x8 a1 = ld8(sA, 16 + lr, RB, HB + ks * 64 + lk * 16);
    bf16x8 a2 = ld8(sA, 32 + lr, RB, HB + ks * 64 + lk * 16);
    bf16x8 a3 = ld8(sA, 48 + lr, RB, HB + ks * 64 + lk * 16);
#pragma unroll
    for (int nf = 0; nf < 2; ++nf) {
      fa[0][nf] = mm(a0, Uff[ks * 2 + nf], fa[0][nf]);
      fa[1][nf] = mm(a1, Uff[ks * 2 + nf], fa[1][nf]);
      fa[2][nf] = mm(a2, Uff[ks * 2 + nf], fa[2][nf]);
      fa[3][nf] = mm(a3, Uff[ks * 2 + nf], fa[3][nf]);
    }
  }
#pragma unroll
  for (int nf = 0; nf < 2; ++nf) {
    const int ch = w * 32 + nf * 16 + lr;
    if constexpr (MODE == 3) {
#pragma unroll
      for (int mf = 0; mf < 4; ++mf)
#pragma unroll
        for (int j = 0; j < 4; ++j) {
          const int nrow = 16 * mf + lk * 4 + j;
          cws[(size_t)sG[nrow] * HS + ch] = sigf(fa[mf][nf][j] + bfa[nf]) * cnv[nf][mf][j];
        }
    } else {
#pragma unroll
      for (int mf = 0; mf < 4; ++mf)
#pragma unroll
        for (int p = 0; p < 2; ++p) {
          const int er = 16 * mf + lk * 4 + 2 * p;
          float f0 = sigf(fa[mf][nf][2 * p]     + bfa[nf]) * cnv[nf][mf][2 * p];
          float f1 = sigf(fa[mf][nf][2 * p + 1] + bfa[nf]) * cnv[nf][mf][2 * p + 1];
          const int gp = sP[er];
          cws[(size_t)gp * HS + ch] = f0 + f1;
          h_bu[(size_t)gp * HS + ch] = (__bf16)(hnv[nf][mf][2 * p] + hnv[nf][mf][2 * p + 1]);
        }
    }
  }
}

// ---------------------------------------------------------------------------
// Merged small-levels kernel (round-9 version).
// ---------------------------------------------------------------------------
__global__ void __launch_bounds__(512, 2)
small_both(const float* __restrict__ Xf,
           const __bf16* __restrict__ Wbu, const float* __restrict__ bbu,
           const __bf16* __restrict__ Ufb, const float* __restrict__ bfb,
           const __bf16* __restrict__ Wtd, const float* __restrict__ btd,
           const __bf16* __restrict__ Uft, const float* __restrict__ bft,
           __bf16* __restrict__ h_bu, __bf16* __restrict__ h_td,
           float* __restrict__ cws)
{
  __shared__ __align__(16) char sX[31 * 256];
  __shared__ __align__(16) char sH[31 * 256];
  __shared__ __align__(16) char sT[16 * 256];
  __shared__ __align__(16) char sTd[15 * 256];
  __shared__ float sCr[16][128];
  __shared__ float sFc[16][128];

  const int tid = threadIdx.x, w = tid >> 6, l = tid & 63, lr = l & 15, lk = l >> 4;
  const int ch = w * 16 + lr;
  const size_t base = (size_t)blockIdx.x * MPT * HS;

  for (int idx = tid; idx < 31 * 16; idx += 512) {
    int n = idx >> 4, e = idx & 15;
    st8(sX, n, 256, e, gx8(Xf + base + (size_t)n * HS + e * 8));
  }
  if (tid < 256) { int n = tid >> 4, e = tid & 15;
    st8(sT, n, 256, e, g8(h_bu + base + (size_t)(15 + n) * HS + e * 8)); }
  { int n = tid >> 5, e = tid & 31;
    reinterpret_cast<float4*>(&sCr[n][0])[e] =
        reinterpret_cast<const float4*>(cws + base + (size_t)(15 + n) * HS)[e]; }
  for (int idx = tid; idx < 15 * 16; idx += 512)
    *reinterpret_cast<float4*>(sTd + idx * 16) = float4{0.f, 0.f, 0.f, 0.f};

  // =================== BU phase: t = 4..0 ===================
  {
    const float bia = bbu[ch], boa = bbu[ch + 128], bua = bbu[ch + 256], bfa = bfb[ch];
    bf16x8 Wb[8][3], Uff[4];
#pragma unroll
    for (int ks = 0; ks < 8; ++ks)
#pragma unroll
      for (int g2 = 0; g2 < 3; ++g2)
        Wb[ks][g2] = g8(Wbu + (size_t)(g2 * 128 + ch) * 256 + ks * 32 + lk * 8);
#pragma unroll
    for (int ks = 0; ks < 4; ++ks)
      Uff[ks] = g8(Ufb + (size_t)ch * HS + ks * 32 + lk * 8);
    __syncthreads();

    for (int t = 4; t >= 0; --t) {
      const int cnt = 1 << t, j0 = cnt - 1;
      f32x4 acc0 = 0.0f, acc1 = 0.0f, acc2 = 0.0f;
      bf16x8 Aa[3];
      auto ldA = [&](int ks, int s) {
        const int kb = (ks & 3) * 64 + lk * 16;
        Aa[s] = (ks < 4) ? ld8(sX, j0 + lr, 256, kb) : ld8(sT, lr, 256, kb);
      };
      ldA(0, 0); ldA(1, 1);
#pragma unroll
      for (int ks = 0; ks < 8; ++ks) {
        if (ks + 2 < 8) ldA(ks + 2, (ks + 2) % 3);
        acc0 = mm(Aa[ks % 3], Wb[ks][0], acc0);
        acc1 = mm(Aa[ks % 3], Wb[ks][1], acc1);
        acc2 = mm(Aa[ks % 3], Wb[ks][2], acc2);
      }
      float cnv[4], hnv[4];
#pragma unroll
      for (int j = 0; j < 4; ++j) {
        const int r = lk * 4 + j;
        float cn = sigf(acc0[j] + bia) * tanh_fast(acc2[j] + bua) + sCr[r][ch];
        float hn = sigf(acc1[j] + boa) * tanh_fast(cn);
        cnv[j] = cn; hnv[j] = hn;
        if (r < cnt) stbf(sH, j0 + r, 256, 2 * ch, hn);
      }
      if (t == 0 && lk == 0) h_bu[base + ch] = (__bf16)hnv[0];
      __syncthreads();
      if (t > 0) {
        f32x4 fa = 0.0f;
#pragma unroll
        for (int ks = 0; ks < 4; ++ks)
          fa = mm(ld8(sH, j0 + lr, 256, ks * 64 + lk * 16), Uff[ks], fa);
#pragma unroll
        for (int p = 0; p < 2; ++p) {
          const int pr = lk * 2 + p;
          if (pr < (cnt >> 1)) {
            float f0 = sigf(fa[2 * p]     + bfa) * cnv[2 * p];
            float f1 = sigf(fa[2 * p + 1] + bfa) * cnv[2 * p + 1];
            sCr[pr][ch] = f0 + f1;
            stbf(sT, pr, 256, 2 * ch, hnv[2 * p] + hnv[2 * p + 1]);
          }
        }
      }
      __syncthreads();
    }
  }

  // =================== TD phase: t = 0..4 ===================
  {
    const float bia = btd[ch], boa = btd[ch + 128], bua = btd[ch + 256], bfa = bft[ch];
    bf16x8 Wt[12][3], Uff[4];
#pragma unroll
    for (int ks = 0; ks < 12; ++ks)
#pragma unroll
      for (int g2 = 0; g2 < 3; ++g2)
        Wt[ks][g2] = g8(Wtd + (size_t)(g2 * 128 + ch) * 384 + ks * 32 + lk * 8);
#pragma unroll
    for (int ks = 0; ks < 4; ++ks)
      Uff[ks] = g8(Uft + (size_t)ch * HS + ks * 32 + lk * 8);

    for (int t = 0; t <= 4; ++t) {
      const int cnt = 1 << t, j0 = cnt - 1;
      f32x4 acc0 = 0.0f, acc1 = 0.0f, acc2 = 0.0f;
      bf16x8 Aa[3];
      auto ldA = [&](int ks, int s) {
        const int kb = (ks & 3) * 64 + lk * 16;
        if (ks < 4)      Aa[s] = ld8(sX, j0 + lr, 256, kb);
        else if (ks < 8) Aa[s] = ld8(sH, j0 + lr, 256, kb);
        else { int pr = (j0 + lr - 1) >> 1; pr = pr < 0 ? 0 : pr;
               Aa[s] = ld8(sTd, pr, 256, kb); }
      };
      ldA(0, 0); ldA(1, 1);
#pragma unroll
      for (int ks = 0; ks < 12; ++ks) {
        if (ks + 2 < 12) ldA(ks + 2, (ks + 2) % 3);
        acc0 = mm(Aa[ks % 3], Wt[ks][0], acc0);
        acc1 = mm(Aa[ks % 3], Wt[ks][1], acc1);
        acc2 = mm(Aa[ks % 3], Wt[ks][2], acc2);
      }
      float cnv[4], hnv[4];
#pragma unroll
      for (int j = 0; j < 4; ++j) {
        const int r = lk * 4 + j;
        float cbv = (t == 0) ? 0.0f : sFc[r >> 1][ch];
        float cn = sigf(acc0[j] + bia) * tanh_fast(acc2[j] + bua) + cbv;
        float hn = sigf(acc1[j] + boa) * tanh_fast(cn);
        cnv[j] = cn; hnv[j] = hn;
        stbf(sT, r, 256, 2 * ch, hn);
        if (r < cnt && j0 + r < 15) stbf(sTd, j0 + r, 256, 2 * ch, hn);
        if (t == 4) h_td[base + (size_t)(15 + r) * HS + ch] = (__bf16)hn;
      }
      __syncthreads();
      f32x4 fa = 0.0f;
#pragma unroll
      for (int ks = 0; ks < 4; ++ks)
        fa = mm(ld8(sT, lr, 256, ks * 64 + lk * 16), Uff[ks], fa);
#pragma unroll
      for (int j = 0; j < 4; ++j) {
        const int r = lk * 4 + j;
        float fcv = sigf(fa[j] + bfa) * cnv[j];
        if (r < cnt) {
          if (t < 4) sFc[r][ch] = fcv;
          else       cws[base + (size_t)(15 + r) * HS + ch] = fcv;
        }
      }
      __syncthreads();
    }
  }
}

// ---------------------------------------------------------------------------
__global__ void __launch_bounds__(256)
prep(const float* __restrict__ Wbu, const float* __restrict__ Ubu,
     const float* __restrict__ Wtd, const float* __restrict__ Utd,
     const float* __restrict__ Ufb, const float* __restrict__ Uft,
     __bf16* wbu, __bf16* wtd, __bf16* ufb, __bf16* uft)
{
  int i = blockIdx.x * 256 + threadIdx.x;
  if (i < 98304) {
    int r = i >> 8, c = i & 255;
    wbu[i] = (__bf16)(c < 128 ? Wbu[r * 128 + c] : Ubu[r * 128 + c - 128]);
  } else if (i < 245760) {
    int k = i - 98304; int r = k / 384, c = k - r * 384;
    wtd[k] = (__bf16)(c < 256 ? Wtd[r * 256 + c] : Utd[r * 128 + (c - 256)]);
  } else if (i < 262144) {
    int k = i - 245760; ufb[k] = (__bf16)Ufb[k];
  } else {
    int k = i - 262144; uft[k] = (__bf16)Uft[k];
  }
}

__global__ void __launch_bounds__(128)
finalize_kernel(const __bf16* __restrict__ h_bu, const float* __restrict__ part,
                float* __restrict__ out)
{
  int b = blockIdx.x, ch = threadIdx.x;
  out[(size_t)b * 256 + ch] = (float)h_bu[((size_t)b * MPT) * HS + ch];
  const float* pp = part + (size_t)b * 1024 + ch;   // 8 partials per tree
  float s = 0.0f;
#pragma unroll
  for (int l2 = 0; l2 < 8; ++l2) s += pp[(size_t)l2 * 128];
  out[(size_t)b * 256 + 128 + ch] = s * (1.0f / 256.0f);
}

extern "C" void kernel_launch(void* const* d_in, const int* in_sizes, int n_in,
                              void* d_out, int out_size, void* d_ws, size_t ws_size,
                              hipStream_t stream) {
  const float* X     = (const float*)d_in[0];
  const float* W_bu  = (const float*)d_in[3];
  const float* U_bu  = (const float*)d_in[4];
  const float* b_bu  = (const float*)d_in[5];
  const float* Uf_bu = (const float*)d_in[6];
  const float* bf_bu = (const float*)d_in[7];
  const float* W_td  = (const float*)d_in[8];
  const float* U_td  = (const float*)d_in[9];
  const float* b_td  = (const float*)d_in[10];
  const float* Uf_td = (const float*)d_in[11];
  const float* bf_td = (const float*)d_in[12];

  char* p = (char*)d_ws;
  __bf16* wbu  = (__bf16*)p; p += (size_t)384 * 256 * 2;
  __bf16* wtd  = (__bf16*)p; p += (size_t)384 * 384 * 2;
  __bf16* ufb  = (__bf16*)p; p += (size_t)128 * 128 * 2;
  __bf16* uft  = (__bf16*)p; p += (size_t)128 * 128 * 2;
  __bf16* h_bu = (__bf16*)p; p += (size_t)NNODE * HS * 2;
  __bf16* h_td = (__bf16*)p; p += (size_t)NNODE * HS * 2;
  float*  cws  = (float*)p;  p += (size_t)NNODE * HS * 4;
  float*  part = (float*)p;  // 2048 * 128 f32

  prep<<<1088, 256, 0, stream>>>(W_bu, U_bu, W_td, U_td, Uf_bu, Uf_td, wbu, wtd, ufb, uft);

  // bottom-up: merged t8+t7 (halved blocks, TLP), then internal t6, t5
  bu_bottom<<<2048, 512, 0, stream>>>(X, wbu, b_bu, ufb, bf_bu, h_bu, cws);
  level_big<1><<<256, 256, 0, stream>>>(6, X, wbu, b_bu, ufb, bf_bu, h_bu, h_td, cws);
  level_big<1><<<128, 256, 0, stream>>>(5, X, wbu, b_bu, ufb, bf_bu, h_bu, h_td, cws);

  // merged small levels: BU t=4..0 + TD t=0..4
  small_both<<<256, 512, 0, stream>>>(X, wbu, b_bu, ufb, bf_bu,
                                      wtd, b_td, uft, bf_td, h_bu, h_td, cws);

  // top-down: t5, t6, then merged t7+t8 (halved blocks, leaf-mean out)
  level_big<3><<<128, 256, 0, stream>>>(5, X, wtd, b_td, uft, bf_td, h_bu, h_td, cws);
  level_big<3><<<256, 256, 0, stream>>>(6, X, wtd, b_td, uft, bf_td, h_bu, h_td, cws);
  td_bottom<<<2048, 512, 0, stream>>>(X, wtd, b_td, uft, bf_td, h_bu, h_td, cws, part);

  finalize_kernel<<<256, 128, 0, stream>>>(h_bu, part, (float*)d_out);
}

// Round 17
// 236.602 us; speedup vs baseline: 1.2597x; 1.2597x over previous
//
#include <hip/hip_runtime.h>
#include <cmath>

#define NTREE 256
#define MPT 511
#define NNODE (NTREE * MPT)   // 130816
#define HS 128

typedef __bf16 bf16x8 __attribute__((ext_vector_type(8)));
typedef float  f32x4  __attribute__((ext_vector_type(4)));

__device__ __forceinline__ float sigf(float x) {
  float e = __builtin_amdgcn_exp2f(x * -1.44269504f);
  return __builtin_amdgcn_rcpf(1.0f + e);
}
__device__ __forceinline__ float tanh_fast(float x) {
  float e = __builtin_amdgcn_exp2f(x * -2.88539008f);
  return __builtin_amdgcn_rcpf(1.0f + e) * 2.0f - 1.0f;
}
__device__ __forceinline__ f32x4 mm(bf16x8 a, bf16x8 b, f32x4 c) {
  return __builtin_amdgcn_mfma_f32_16x16x32_bf16(a, b, c, 0, 0, 0);
}
// XOR-swizzled LDS tile helpers (T2): row-major bf16, 16B chunk swizzle
__device__ __forceinline__ int swz(int row, int rb, int kb) { return row * rb + (kb ^ ((row & 7) << 4)); }
__device__ __forceinline__ void st8(char* s, int row, int rb, int chunk, bf16x8 v) {
  *reinterpret_cast<bf16x8*>(s + swz(row, rb, chunk * 16)) = v;
}
__device__ __forceinline__ bf16x8 ld8(const char* s, int row, int rb, int kb) {
  return *reinterpret_cast<const bf16x8*>(s + swz(row, rb, kb));
}
__device__ __forceinline__ bf16x8 g8(const __bf16* p) { return *reinterpret_cast<const bf16x8*>(p); }
__device__ __forceinline__ bf16x8 gx8(const float* p) {   // f32 row -> bf16x8
  float4 v0 = reinterpret_cast<const float4*>(p)[0];
  float4 v1 = reinterpret_cast<const float4*>(p)[1];
  bf16x8 o;
  o[0] = (__bf16)v0.x; o[1] = (__bf16)v0.y; o[2] = (__bf16)v0.z; o[3] = (__bf16)v0.w;
  o[4] = (__bf16)v1.x; o[5] = (__bf16)v1.y; o[6] = (__bf16)v1.z; o[7] = (__bf16)v1.w;
  return o;
}
__device__ __forceinline__ void stbf(char* s, int row, int rb, int kbyte, float v) {
  *reinterpret_cast<__bf16*>(s + row * rb + (kbyte ^ ((row & 7) << 4))) = (__bf16)v;
}

// ---------------------------------------------------------------------------
// BU bottom: one block = 32 t7-nodes + their 64 leaf children. 512 thr, 8
// waves, wave = 16-ch slice. (512,1): 256-VGPR budget for the W preload.
// Leaf htild/cred stay in LDS; t7 computed in-block; epilogue pushes t6.
// LDS 48KB -> 2-3 blocks/CU possible.
// ---------------------------------------------------------------------------
__global__ void __launch_bounds__(512, 1)
bu_bottom(const float* __restrict__ Xf,
          const __bf16* __restrict__ W, const float* __restrict__ bp,
          const __bf16* __restrict__ Uf, const float* __restrict__ bf_,
          __bf16* __restrict__ h_bu, float* __restrict__ cws)
{
  __shared__ __align__(16) char sX8[64 * 256];   // leaf x, then h-bounce (16KB)
  __shared__ __align__(16) char sX7[32 * 256];   // t7 x, then h-bounce (8KB)
  __shared__ __align__(16) char sT [32 * 256];   // htild for t7 (8KB)
  __shared__ float sCr[32][128];                 // cred for t7 (16KB)

  const int tid = threadIdx.x, w = tid >> 6, l = tid & 63, lr = l & 15, lk = l >> 4;
  const int ch = w * 16 + lr;
  const int vb = blockIdx.x * 32;
  const int b  = vb >> 7;
  const int j7 = 127 + (vb & 127);                      // t=7 starts at 127 (odd)
  const size_t g7  = (size_t)b * MPT + j7;
  const size_t gLf = (size_t)b * MPT + 2 * j7 + 1;
  const size_t gp6 = (size_t)b * MPT + ((j7 - 1) >> 1);

  // ---- whole-kernel weights (issued first) ----
  bf16x8 Wb[8][3], Uff[4];
#pragma unroll
  for (int ks = 0; ks < 8; ++ks)
#pragma unroll
    for (int g2 = 0; g2 < 3; ++g2)
      Wb[ks][g2] = g8(W + (size_t)(g2 * 128 + ch) * 256 + ks * 32 + lk * 8);
#pragma unroll
  for (int ks = 0; ks < 4; ++ks) Uff[ks] = g8(Uf + (size_t)ch * HS + ks * 32 + lk * 8);

  // ---- stage leaf x (64 rows) + t7 x (32 rows), one batch ----
#pragma unroll
  for (int it = 0; it < 2; ++it) {
    int idx = tid + it * 512, n = idx >> 4, e = idx & 15;
    st8(sX8, n, 256, e, gx8(Xf + (gLf + n) * HS + e * 8));
  }
  { int n = tid >> 4, e = tid & 15;
    st8(sX7, n, 256, e, gx8(Xf + (g7 + n) * HS + e * 8)); }

  const float bia = bp[ch], boa = bp[ch + 128], bua = bp[ch + 256], bfa = bf_[ch];
  __syncthreads();

  // ================= leaf phase: M=64, K=128 =================
  f32x4 acc[3][4];
#pragma unroll
  for (int g2 = 0; g2 < 3; ++g2)
#pragma unroll
    for (int mf = 0; mf < 4; ++mf) acc[g2][mf] = 0.0f;

#pragma unroll
  for (int ks = 0; ks < 4; ++ks) {
    const int kb = ks * 64 + lk * 16;
    bf16x8 A0 = ld8(sX8, lr,      256, kb);
    bf16x8 A1 = ld8(sX8, 16 + lr, 256, kb);
    bf16x8 A2 = ld8(sX8, 32 + lr, 256, kb);
    bf16x8 A3 = ld8(sX8, 48 + lr, 256, kb);
#pragma unroll
    for (int g2 = 0; g2 < 3; ++g2) {
      acc[g2][0] = mm(A0, Wb[ks][g2], acc[g2][0]);
      acc[g2][1] = mm(A1, Wb[ks][g2], acc[g2][1]);
      acc[g2][2] = mm(A2, Wb[ks][g2], acc[g2][2]);
      acc[g2][3] = mm(A3, Wb[ks][g2], acc[g2][3]);
    }
  }
  float cnv[4][4], hnv[4][4];
#pragma unroll
  for (int mf = 0; mf < 4; ++mf)
#pragma unroll
    for (int j = 0; j < 4; ++j) {
      const int nrow = 16 * mf + lk * 4 + j;
      float cn = sigf(acc[0][mf][j] + bia) * tanh_fast(acc[2][mf][j] + bua);
      float hn = sigf(acc[1][mf][j] + boa) * tanh_fast(cn);
      cnv[mf][j] = cn; hnv[mf][j] = hn;
      h_bu[(gLf + nrow) * HS + ch] = (__bf16)hn;
    }
  __syncthreads();
#pragma unroll
  for (int mf = 0; mf < 4; ++mf)
#pragma unroll
    for (int j = 0; j < 4; ++j)
      stbf(sX8, 16 * mf + lk * 4 + j, 256, 2 * ch, hnv[mf][j]);
  __syncthreads();
  {
    f32x4 fa[4];
#pragma unroll
    for (int mf = 0; mf < 4; ++mf) fa[mf] = 0.0f;
#pragma unroll
    for (int ks = 0; ks < 4; ++ks) {
      const int kb = ks * 64 + lk * 16;
      fa[0] = mm(ld8(sX8, lr,      256, kb), Uff[ks], fa[0]);
      fa[1] = mm(ld8(sX8, 16 + lr, 256, kb), Uff[ks], fa[1]);
      fa[2] = mm(ld8(sX8, 32 + lr, 256, kb), Uff[ks], fa[2]);
      fa[3] = mm(ld8(sX8, 48 + lr, 256, kb), Uff[ks], fa[3]);
    }
#pragma unroll
    for (int mf = 0; mf < 4; ++mf)
#pragma unroll
      for (int p = 0; p < 2; ++p) {
        const int er = 16 * mf + lk * 4 + 2 * p;
        const int pr = er >> 1;
        float f0 = sigf(fa[mf][2 * p]     + bfa) * cnv[mf][2 * p];
        float f1 = sigf(fa[mf][2 * p + 1] + bfa) * cnv[mf][2 * p + 1];
        sCr[pr][ch] = f0 + f1;
        stbf(sT, pr, 256, 2 * ch, hnv[mf][2 * p] + hnv[mf][2 * p + 1]);
      }
  }
  __syncthreads();

  // ================= t7 phase: M=32, K=256 ([x | htild]) =================
  f32x4 ac2[3][2];
#pragma unroll
  for (int g2 = 0; g2 < 3; ++g2) { ac2[g2][0] = 0.0f; ac2[g2][1] = 0.0f; }
#pragma unroll
  for (int ks = 0; ks < 8; ++ks) {
    const int kb = (ks & 3) * 64 + lk * 16;
    bf16x8 A0 = (ks < 4) ? ld8(sX7, lr,      256, kb) : ld8(sT, lr,      256, kb);
    bf16x8 A1 = (ks < 4) ? ld8(sX7, 16 + lr, 256, kb) : ld8(sT, 16 + lr, 256, kb);
#pragma unroll
    for (int g2 = 0; g2 < 3; ++g2) {
      ac2[g2][0] = mm(A0, Wb[ks][g2], ac2[g2][0]);
      ac2[g2][1] = mm(A1, Wb[ks][g2], ac2[g2][1]);
    }
  }
  float cn2[2][4], hn2[2][4];
#pragma unroll
  for (int mf = 0; mf < 2; ++mf)
#pragma unroll
    for (int j = 0; j < 4; ++j) {
      const int nr = 16 * mf + lk * 4 + j;
      float cn = sigf(ac2[0][mf][j] + bia) * tanh_fast(ac2[2][mf][j] + bua) + sCr[nr][ch];
      float hn = sigf(ac2[1][mf][j] + boa) * tanh_fast(cn);
      cn2[mf][j] = cn; hn2[mf][j] = hn;
      h_bu[(g7 + nr) * HS + ch] = (__bf16)hn;
    }
  __syncthreads();
#pragma unroll
  for (int mf = 0; mf < 2; ++mf)
#pragma unroll
    for (int j = 0; j < 4; ++j)
      stbf(sX7, 16 * mf + lk * 4 + j, 256, 2 * ch, hn2[mf][j]);
  __syncthreads();
  {
    f32x4 fb[2]; fb[0] = 0.0f; fb[1] = 0.0f;
#pragma unroll
    for (int ks = 0; ks < 4; ++ks) {
      const int kb = ks * 64 + lk * 16;
      fb[0] = mm(ld8(sX7, lr,      256, kb), Uff[ks], fb[0]);
      fb[1] = mm(ld8(sX7, 16 + lr, 256, kb), Uff[ks], fb[1]);
    }
#pragma unroll
    for (int mf = 0; mf < 2; ++mf)
#pragma unroll
      for (int p = 0; p < 2; ++p) {
        const int er = 16 * mf + lk * 4 + 2 * p;
        const size_t gp = gp6 + (er >> 1);
        float f0 = sigf(fb[mf][2 * p]     + bfa) * cn2[mf][2 * p];
        float f1 = sigf(fb[mf][2 * p + 1] + bfa) * cn2[mf][2 * p + 1];
        cws[gp * HS + ch] = f0 + f1;
        h_bu[gp * HS + ch] = (__bf16)(hn2[mf][2 * p] + hn2[mf][2 * p + 1]);
      }
  }
}

// ---------------------------------------------------------------------------
// TD bottom: one block = 32 t7-nodes + 64 leaf children. Parent h_td rows
// DE-DUPLICATED into sPar[16] (read with row>>1 pairing) -> LDS 76KB so two
// blocks fit per CU (was exact-fit 80KB -> 1 block).
// ---------------------------------------------------------------------------
__global__ void __launch_bounds__(512, 1)
td_bottom(const float* __restrict__ Xf,
          const __bf16* __restrict__ W, const float* __restrict__ bp,
          const __bf16* __restrict__ Uf, const float* __restrict__ bf_,
          const __bf16* __restrict__ h_bu, const __bf16* __restrict__ h_td,
          const float* __restrict__ cws, float* __restrict__ part)
{
  __shared__ __align__(16) char sA7[32 * 512];   // t7 [x | h_bu] (16KB)
  __shared__ __align__(16) char sPar[16 * 256];  // t6 parent h_td (4KB)
  __shared__ __align__(16) char sXH[64 * 512];   // leaves [x | h_bu] (32KB)
  __shared__ __align__(16) char sTd[32 * 256];   // h_td t7 (8KB)
  __shared__ float sFc[32][128];                 // fc t7 (16KB)

  const int tid = threadIdx.x, w = tid >> 6, l = tid & 63, lr = l & 15, lk = l >> 4;
  const int ch = w * 16 + lr;
  const int vb = blockIdx.x * 32;
  const int b  = vb >> 7;
  const int j7 = 127 + (vb & 127);
  const size_t g7  = (size_t)b * MPT + j7;
  const size_t gLf = (size_t)b * MPT + 2 * j7 + 1;
  const size_t gp6 = (size_t)b * MPT + ((j7 - 1) >> 1);

  // ---- whole-kernel weights (issued first) ----
  bf16x8 Wt[12][3], Uff[4];
#pragma unroll
  for (int ks = 0; ks < 12; ++ks)
#pragma unroll
    for (int g2 = 0; g2 < 3; ++g2)
      Wt[ks][g2] = g8(W + (size_t)(g2 * 128 + ch) * 384 + ks * 32 + lk * 8);
#pragma unroll
  for (int ks = 0; ks < 4; ++ks) Uff[ks] = g8(Uf + (size_t)ch * HS + ks * 32 + lk * 8);

  // ---- stage everything in one batch ----
  { int n = tid >> 4, e = tid & 15;    // t7 rows: [x | h_bu]
    st8(sA7, n, 512, e,      gx8(Xf   + (g7 + n) * HS + e * 8));
    st8(sA7, n, 512, 16 + e, g8(h_bu + (g7 + n) * HS + e * 8)); }
  if (tid < 256) { int n = tid >> 4, e = tid & 15;  // 16 distinct t6 parents
    st8(sPar, n, 256, e, g8(h_td + (gp6 + n) * HS + e * 8)); }
#pragma unroll
  for (int it = 0; it < 2; ++it) {     // leaf rows
    int idx = tid + it * 512, n = idx >> 4, e = idx & 15;
    st8(sXH, n, 512, e,      gx8(Xf   + (gLf + n) * HS + e * 8));
    st8(sXH, n, 512, 16 + e, g8(h_bu + (gLf + n) * HS + e * 8));
  }
  float cb[2][4];
#pragma unroll
  for (int mf = 0; mf < 2; ++mf)
#pragma unroll
    for (int j = 0; j < 4; ++j) {
      const int nr = 16 * mf + lk * 4 + j;
      cb[mf][j] = cws[(gp6 + (nr >> 1)) * HS + ch];
    }
  const float bia = bp[ch], boa = bp[ch + 128], bua = bp[ch + 256], bfa = bf_[ch];
  __syncthreads();

  // ================= t7 phase: M=32, K=384 ([x|h_bu] + parent) =============
  f32x4 ac[3][2];
#pragma unroll
  for (int g2 = 0; g2 < 3; ++g2) { ac[g2][0] = 0.0f; ac[g2][1] = 0.0f; }
#pragma unroll
  for (int ks = 0; ks < 12; ++ks) {
    bf16x8 A0, A1;
    if (ks < 8) {
      const int kb = ks * 64 + lk * 16;
      A0 = ld8(sA7, lr,      512, kb);
      A1 = ld8(sA7, 16 + lr, 512, kb);
    } else {
      const int kb = (ks - 8) * 64 + lk * 16;
      A0 = ld8(sPar, (lr >> 1),     256, kb);
      A1 = ld8(sPar, 8 + (lr >> 1), 256, kb);
    }
#pragma unroll
    for (int g2 = 0; g2 < 3; ++g2) {
      ac[g2][0] = mm(A0, Wt[ks][g2], ac[g2][0]);
      ac[g2][1] = mm(A1, Wt[ks][g2], ac[g2][1]);
    }
  }
  float cn7[2][4];
#pragma unroll
  for (int mf = 0; mf < 2; ++mf)
#pragma unroll
    for (int j = 0; j < 4; ++j) {
      const int nr = 16 * mf + lk * 4 + j;
      float cn = sigf(ac[0][mf][j] + bia) * tanh_fast(ac[2][mf][j] + bua) + cb[mf][j];
      float hn = sigf(ac[1][mf][j] + boa) * tanh_fast(cn);
      cn7[mf][j] = cn;
      stbf(sTd, nr, 256, 2 * ch, hn);
    }
  __syncthreads();
  {
    f32x4 fa[2]; fa[0] = 0.0f; fa[1] = 0.0f;
#pragma unroll
    for (int ks = 0; ks < 4; ++ks) {
      const int kb = ks * 64 + lk * 16;
      fa[0] = mm(ld8(sTd, lr,      256, kb), Uff[ks], fa[0]);
      fa[1] = mm(ld8(sTd, 16 + lr, 256, kb), Uff[ks], fa[1]);
    }
#pragma unroll
    for (int mf = 0; mf < 2; ++mf)
#pragma unroll
      for (int j = 0; j < 4; ++j) {
        const int nr = 16 * mf + lk * 4 + j;
        sFc[nr][ch] = sigf(fa[mf][j] + bfa) * cn7[mf][j];
      }
  }
  __syncthreads();

  // ================= leaf phase: M=64, K=384, LEAFOUT =================
  f32x4 a8[3][4];
#pragma unroll
  for (int g2 = 0; g2 < 3; ++g2)
#pragma unroll
    for (int mf = 0; mf < 4; ++mf) a8[g2][mf] = 0.0f;
#pragma unroll
  for (int ks = 0; ks < 12; ++ks) {
    bf16x8 A0, A1, A2, A3;
    if (ks < 8) {
      const int kb = ks * 64 + lk * 16;
      A0 = ld8(sXH, lr,      512, kb);
      A1 = ld8(sXH, 16 + lr, 512, kb);
      A2 = ld8(sXH, 32 + lr, 512, kb);
      A3 = ld8(sXH, 48 + lr, 512, kb);
    } else {
      const int kb = (ks - 8) * 64 + lk * 16;
      A0 = ld8(sTd, (lr >> 1),      256, kb);
      A1 = ld8(sTd, 8 + (lr >> 1),  256, kb);
      A2 = ld8(sTd, 16 + (lr >> 1), 256, kb);
      A3 = ld8(sTd, 24 + (lr >> 1), 256, kb);
    }
#pragma unroll
    for (int g2 = 0; g2 < 3; ++g2) {
      a8[g2][0] = mm(A0, Wt[ks][g2], a8[g2][0]);
      a8[g2][1] = mm(A1, Wt[ks][g2], a8[g2][1]);
      a8[g2][2] = mm(A2, Wt[ks][g2], a8[g2][2]);
      a8[g2][3] = mm(A3, Wt[ks][g2], a8[g2][3]);
    }
  }
  float psum = 0.0f;
#pragma unroll
  for (int mf = 0; mf < 4; ++mf)
#pragma unroll
    for (int j = 0; j < 4; ++j) {
      const int nrow = 16 * mf + lk * 4 + j;
      float cbase = sFc[nrow >> 1][ch];
      float cn = sigf(a8[0][mf][j] + bia) * tanh_fast(a8[2][mf][j] + bua) + cbase;
      float hn = sigf(a8[1][mf][j] + boa) * tanh_fast(cn);
      psum += hn;
    }
  float s = psum;
  s += __shfl_xor(s, 16);
  s += __shfl_xor(s, 32);
  if (lk == 0) part[(size_t)blockIdx.x * 128 + ch] = s;
}

// ---------------------------------------------------------------------------
// Mid-level kernel (round-9 structure, unchanged): 64 nodes/block, 4 waves.
// MODE: 1 = BU internal (K=256), 3 = TD (K=384). Always EPI.
// ---------------------------------------------------------------------------
template <int MODE>
__global__ void __launch_bounds__(256, 2)
level_big(int t,
          const float*  __restrict__ Xf,
          const __bf16* __restrict__ W,
          const float*  __restrict__ bp,
          const __bf16* __restrict__ Uf,
          const float*  __restrict__ bf_,
          __bf16* __restrict__ h_bu,
          __bf16* __restrict__ h_td,
          float*  __restrict__ cws)
{
  constexpr int KA = (MODE == 1) ? 256 : 384;
  constexpr int KS = KA / 32;
  constexpr int BK = (MODE == 3) ? 384 : 256;
  constexpr int RB = KA * 2;
  constexpr int HB = (MODE == 1) ? 256 : 512;

  __shared__ __align__(16) char sA[64 * RB];
  __shared__ int sG[64], sP[64];

  const int tid = threadIdx.x;
  const int w = tid >> 6, l = tid & 63, lr = l & 15, lk = l >> 4;

  if (tid < 64) {
    int v = blockIdx.x * 64 + tid;
    int b = v >> t;
    int j = (1 << t) - 1 + (v & ((1 << t) - 1));
    sG[tid] = b * MPT + j;
    sP[tid] = b * MPT + ((j - 1) >> 1);
  }
  __syncthreads();

#pragma unroll
  for (int it = 0; it < 4; ++it) {
    int idx = tid + it * 256, n = idx >> 4, e = idx & 15;
    st8(sA, n, RB, e, gx8(Xf + (size_t)sG[n] * HS + e * 8));
  }
#pragma unroll
  for (int it = 0; it < 4; ++it) {
    int idx = tid + it * 256, n = idx >> 4, e = idx & 15;
    st8(sA, n, RB, 16 + e, g8(h_bu + (size_t)sG[n] * HS + e * 8));
  }
  if constexpr (MODE == 3) {
#pragma unroll
    for (int it = 0; it < 4; ++it) {
      int idx = tid + it * 256, n = idx >> 4, e = idx & 15;
      st8(sA, n, RB, 32 + e, g8(h_td + (size_t)sP[n] * HS + e * 8));
    }
  }
  __syncthreads();

  float cb[2][4][4];
  float bia[2], boa[2], bua[2], bfa[2];
#pragma unroll
  for (int nf = 0; nf < 2; ++nf) {
    const int ch = w * 32 + nf * 16 + lr;
    bia[nf] = bp[ch]; boa[nf] = bp[ch + 128]; bua[nf] = bp[ch + 256];
    bfa[nf] = bf_[ch];
#pragma unroll
    for (int mf = 0; mf < 4; ++mf)
#pragma unroll
      for (int j = 0; j < 4; ++j) {
        const int nrow = 16 * mf + lk * 4 + j;
        const int src = (MODE == 1) ? sG[nrow] : sP[nrow];
        cb[nf][mf][j] = cws[(size_t)src * HS + ch];
      }
  }

  f32x4 acc[6][4];
#pragma unroll
  for (int p = 0; p < 6; ++p)
#pragma unroll
    for (int mf = 0; mf < 4; ++mf) acc[p][mf] = 0.0f;

  bf16x8 A0[4], A1[4], Bb[3][6];
  auto ldA = [&](int ks, bf16x8* Ad) {
#pragma unroll
    for (int mf = 0; mf < 4; ++mf) Ad[mf] = ld8(sA, mf * 16 + lr, RB, ks * 64 + lk * 16);
  };
  auto ldB = [&](int ks, int s) {
#pragma unroll
    for (int g2 = 0; g2 < 3; ++g2)
#pragma unroll
      for (int nf = 0; nf < 2; ++nf)
        Bb[s][g2 * 2 + nf] = g8(W + (size_t)(g2 * 128 + w * 32 + nf * 16 + lr) * BK + ks * 32 + lk * 8);
  };

  ldB(0, 0); ldA(0, A0); ldB(1, 1);
#pragma unroll
  for (int ks = 0; ks < KS; ++ks) {
    bf16x8* Ac = (ks & 1) ? A1 : A0;
    bf16x8* An = (ks & 1) ? A0 : A1;
    if (ks + 1 < KS) ldA(ks + 1, An);
    if (ks + 2 < KS) ldB(ks + 2, (ks + 2) % 3);
#pragma unroll
    for (int p = 0; p < 6; ++p)
#pragma unroll
      for (int mf = 0; mf < 4; ++mf) acc[p][mf] = mm(Ac[mf], Bb[ks % 3][p], acc[p][mf]);
  }

  bf16x8 Uff[8];
#pragma unroll
  for (int ks = 0; ks < 4; ++ks)
#pragma unroll
    for (int nf = 0; nf < 2; ++nf)
      Uff[ks * 2 + nf] = g8(Uf + (size_t)(w * 32 + nf * 16 + lr) * HS + ks * 32 + lk * 8);

  __bf16* hp = (MODE == 3) ? h_td : h_bu;
  float cnv[2][4][4], hnv[2][4][4];
#pragma unroll
  for (int nf = 0; nf < 2; ++nf) {
    const int ch = w * 32 + nf * 16 + lr;
#pragma unroll
    for (int mf = 0; mf < 4; ++mf)
#pragma unroll
      for (int j = 0; j < 4; ++j) {
        const int nrow = 16 * mf + lk * 4 + j;
        float cn = sigf(acc[nf][mf][j] + bia[nf]) * tanh_fast(acc[4 + nf][mf][j] + bua[nf]) + cb[nf][mf][j];
        float hn = sigf(acc[2 + nf][mf][j] + boa[nf]) * tanh_fast(cn);
        hp[(size_t)sG[nrow] * HS + ch] = (__bf16)hn;
        cnv[nf][mf][j] = cn; hnv[nf][mf][j] = hn;
      }
  }

  __syncthreads();
#pragma unroll
  for (int nf = 0; nf < 2; ++nf) {
    const int ch = w * 32 + nf * 16 + lr;
#pragma unroll
    for (int mf = 0; mf < 4; ++mf)
#pragma unroll
      for (int j = 0; j < 4; ++j)
        stbf(sA, 16 * mf + lk * 4 + j, RB, HB + 2 * ch, hnv[nf][mf][j]);
  }
  __syncthreads();
  f32x4 fa[4][2];
#pragma unroll
  for (int mf = 0; mf < 4; ++mf) { fa[mf][0] = 0.0f; fa[mf][1] = 0.0f; }
#pragma unroll
  for (int ks = 0; ks < 4; ++ks) {
    bf16x8 a0 = ld8(sA, lr,      RB, HB + ks * 64 + lk * 16);
    bf16x8 a1 = ld8(sA, 16 + lr, RB, HB + ks * 64 + lk * 16);
    bf16x8 a2 = ld8(sA, 32 + lr, RB, HB + ks * 64 + lk * 16);
    bf16x8 a3 = ld8(sA, 48 + lr, RB, HB + ks * 64 + lk * 16);
#pragma unroll
    for (int nf = 0; nf < 2; ++nf) {
      fa[0][nf] = mm(a0, Uff[ks * 2 + nf], fa[0][nf]);
      fa[1][nf] = mm(a1, Uff[ks * 2 + nf], fa[1][nf]);
      fa[2][nf] = mm(a2, Uff[ks * 2 + nf], fa[2][nf]);
      fa[3][nf] = mm(a3, Uff[ks * 2 + nf], fa[3][nf]);
    }
  }
#pragma unroll
  for (int nf = 0; nf < 2; ++nf) {
    const int ch = w * 32 + nf * 16 + lr;
    if constexpr (MODE == 3) {
#pragma unroll
      for (int mf = 0; mf < 4; ++mf)
#pragma unroll
        for (int j = 0; j < 4; ++j) {
          const int nrow = 16 * mf + lk * 4 + j;
          cws[(size_t)sG[nrow] * HS + ch] = sigf(fa[mf][nf][j] + bfa[nf]) * cnv[nf][mf][j];
        }
    } else {
#pragma unroll
      for (int mf = 0; mf < 4; ++mf)
#pragma unroll
        for (int p = 0; p < 2; ++p) {
          const int er = 16 * mf + lk * 4 + 2 * p;
          float f0 = sigf(fa[mf][nf][2 * p]     + bfa[nf]) * cnv[nf][mf][2 * p];
          float f1 = sigf(fa[mf][nf][2 * p + 1] + bfa[nf]) * cnv[nf][mf][2 * p + 1];
          const int gp = sP[er];
          cws[(size_t)gp * HS + ch] = f0 + f1;
          h_bu[(size_t)gp * HS + ch] = (__bf16)(hnv[nf][mf][2 * p] + hnv[nf][mf][2 * p + 1]);
        }
    }
  }
}

// ---------------------------------------------------------------------------
// Merged small-levels kernel (round-9 version).
// ---------------------------------------------------------------------------
__global__ void __launch_bounds__(512, 2)
small_both(const float* __restrict__ Xf,
           const __bf16* __restrict__ Wbu, const float* __restrict__ bbu,
           const __bf16* __restrict__ Ufb, const float* __restrict__ bfb,
           const __bf16* __restrict__ Wtd, const float* __restrict__ btd,
           const __bf16* __restrict__ Uft, const float* __restrict__ bft,
           __bf16* __restrict__ h_bu, __bf16* __restrict__ h_td,
           float* __restrict__ cws)
{
  __shared__ __align__(16) char sX[31 * 256];
  __shared__ __align__(16) char sH[31 * 256];
  __shared__ __align__(16) char sT[16 * 256];
  __shared__ __align__(16) char sTd[15 * 256];
  __shared__ float sCr[16][128];
  __shared__ float sFc[16][128];

  const int tid = threadIdx.x, w = tid >> 6, l = tid & 63, lr = l & 15, lk = l >> 4;
  const int ch = w * 16 + lr;
  const size_t base = (size_t)blockIdx.x * MPT * HS;

  for (int idx = tid; idx < 31 * 16; idx += 512) {
    int n = idx >> 4, e = idx & 15;
    st8(sX, n, 256, e, gx8(Xf + base + (size_t)n * HS + e * 8));
  }
  if (tid < 256) { int n = tid >> 4, e = tid & 15;
    st8(sT, n, 256, e, g8(h_bu + base + (size_t)(15 + n) * HS + e * 8)); }
  { int n = tid >> 5, e = tid & 31;
    reinterpret_cast<float4*>(&sCr[n][0])[e] =
        reinterpret_cast<const float4*>(cws + base + (size_t)(15 + n) * HS)[e]; }
  for (int idx = tid; idx < 15 * 16; idx += 512)
    *reinterpret_cast<float4*>(sTd + idx * 16) = float4{0.f, 0.f, 0.f, 0.f};

  // =================== BU phase: t = 4..0 ===================
  {
    const float bia = bbu[ch], boa = bbu[ch + 128], bua = bbu[ch + 256], bfa = bfb[ch];
    bf16x8 Wb[8][3], Uff[4];
#pragma unroll
    for (int ks = 0; ks < 8; ++ks)
#pragma unroll
      for (int g2 = 0; g2 < 3; ++g2)
        Wb[ks][g2] = g8(Wbu + (size_t)(g2 * 128 + ch) * 256 + ks * 32 + lk * 8);
#pragma unroll
    for (int ks = 0; ks < 4; ++ks)
      Uff[ks] = g8(Ufb + (size_t)ch * HS + ks * 32 + lk * 8);
    __syncthreads();

    for (int t = 4; t >= 0; --t) {
      const int cnt = 1 << t, j0 = cnt - 1;
      f32x4 acc0 = 0.0f, acc1 = 0.0f, acc2 = 0.0f;
      bf16x8 Aa[3];
      auto ldA = [&](int ks, int s) {
        const int kb = (ks & 3) * 64 + lk * 16;
        Aa[s] = (ks < 4) ? ld8(sX, j0 + lr, 256, kb) : ld8(sT, lr, 256, kb);
      };
      ldA(0, 0); ldA(1, 1);
#pragma unroll
      for (int ks = 0; ks < 8; ++ks) {
        if (ks + 2 < 8) ldA(ks + 2, (ks + 2) % 3);
        acc0 = mm(Aa[ks % 3], Wb[ks][0], acc0);
        acc1 = mm(Aa[ks % 3], Wb[ks][1], acc1);
        acc2 = mm(Aa[ks % 3], Wb[ks][2], acc2);
      }
      float cnv[4], hnv[4];
#pragma unroll
      for (int j = 0; j < 4; ++j) {
        const int r = lk * 4 + j;
        float cn = sigf(acc0[j] + bia) * tanh_fast(acc2[j] + bua) + sCr[r][ch];
        float hn = sigf(acc1[j] + boa) * tanh_fast(cn);
        cnv[j] = cn; hnv[j] = hn;
        if (r < cnt) stbf(sH, j0 + r, 256, 2 * ch, hn);
      }
      if (t == 0 && lk == 0) h_bu[base + ch] = (__bf16)hnv[0];
      __syncthreads();
      if (t > 0) {
        f32x4 fa = 0.0f;
#pragma unroll
        for (int ks = 0; ks < 4; ++ks)
          fa = mm(ld8(sH, j0 + lr, 256, ks * 64 + lk * 16), Uff[ks], fa);
#pragma unroll
        for (int p = 0; p < 2; ++p) {
          const int pr = lk * 2 + p;
          if (pr < (cnt >> 1)) {
            float f0 = sigf(fa[2 * p]     + bfa) * cnv[2 * p];
            float f1 = sigf(fa[2 * p + 1] + bfa) * cnv[2 * p + 1];
            sCr[pr][ch] = f0 + f1;
            stbf(sT, pr, 256, 2 * ch, hnv[2 * p] + hnv[2 * p + 1]);
          }
        }
      }
      __syncthreads();
    }
  }

  // =================== TD phase: t = 0..4 ===================
  {
    const float bia = btd[ch], boa = btd[ch + 128], bua = btd[ch + 256], bfa = bft[ch];
    bf16x8 Wt[12][3], Uff[4];
#pragma unroll
    for (int ks = 0; ks < 12; ++ks)
#pragma unroll
      for (int g2 = 0; g2 < 3; ++g2)
        Wt[ks][g2] = g8(Wtd + (size_t)(g2 * 128 + ch) * 384 + ks * 32 + lk * 8);
#pragma unroll
    for (int ks = 0; ks < 4; ++ks)
      Uff[ks] = g8(Uft + (size_t)ch * HS + ks * 32 + lk * 8);

    for (int t = 0; t <= 4; ++t) {
      const int cnt = 1 << t, j0 = cnt - 1;
      f32x4 acc0 = 0.0f, acc1 = 0.0f, acc2 = 0.0f;
      bf16x8 Aa[3];
      auto ldA = [&](int ks, int s) {
        const int kb = (ks & 3) * 64 + lk * 16;
        if (ks < 4)      Aa[s] = ld8(sX, j0 + lr, 256, kb);
        else if (ks < 8) Aa[s] = ld8(sH, j0 + lr, 256, kb);
        else { int pr = (j0 + lr - 1) >> 1; pr = pr < 0 ? 0 : pr;
               Aa[s] = ld8(sTd, pr, 256, kb); }
      };
      ldA(0, 0); ldA(1, 1);
#pragma unroll
      for (int ks = 0; ks < 12; ++ks) {
        if (ks + 2 < 12) ldA(ks + 2, (ks + 2) % 3);
        acc0 = mm(Aa[ks % 3], Wt[ks][0], acc0);
        acc1 = mm(Aa[ks % 3], Wt[ks][1], acc1);
        acc2 = mm(Aa[ks % 3], Wt[ks][2], acc2);
      }
      float cnv[4], hnv[4];
#pragma unroll
      for (int j = 0; j < 4; ++j) {
        const int r = lk * 4 + j;
        float cbv = (t == 0) ? 0.0f : sFc[r >> 1][ch];
        float cn = sigf(acc0[j] + bia) * tanh_fast(acc2[j] + bua) + cbv;
        float hn = sigf(acc1[j] + boa) * tanh_fast(cn);
        cnv[j] = cn; hnv[j] = hn;
        stbf(sT, r, 256, 2 * ch, hn);
        if (r < cnt && j0 + r < 15) stbf(sTd, j0 + r, 256, 2 * ch, hn);
        if (t == 4) h_td[base + (size_t)(15 + r) * HS + ch] = (__bf16)hn;
      }
      __syncthreads();
      f32x4 fa = 0.0f;
#pragma unroll
      for (int ks = 0; ks < 4; ++ks)
        fa = mm(ld8(sT, lr, 256, ks * 64 + lk * 16), Uff[ks], fa);
#pragma unroll
      for (int j = 0; j < 4; ++j) {
        const int r = lk * 4 + j;
        float fcv = sigf(fa[j] + bfa) * cnv[j];
        if (r < cnt) {
          if (t < 4) sFc[r][ch] = fcv;
          else       cws[base + (size_t)(15 + r) * HS + ch] = fcv;
        }
      }
      __syncthreads();
    }
  }
}

// ---------------------------------------------------------------------------
__global__ void __launch_bounds__(256)
prep(const float* __restrict__ Wbu, const float* __restrict__ Ubu,
     const float* __restrict__ Wtd, const float* __restrict__ Utd,
     const float* __restrict__ Ufb, const float* __restrict__ Uft,
     __bf16* wbu, __bf16* wtd, __bf16* ufb, __bf16* uft)
{
  int i = blockIdx.x * 256 + threadIdx.x;
  if (i < 98304) {
    int r = i >> 8, c = i & 255;
    wbu[i] = (__bf16)(c < 128 ? Wbu[r * 128 + c] : Ubu[r * 128 + c - 128]);
  } else if (i < 245760) {
    int k = i - 98304; int r = k / 384, c = k - r * 384;
    wtd[k] = (__bf16)(c < 256 ? Wtd[r * 256 + c] : Utd[r * 128 + (c - 256)]);
  } else if (i < 262144) {
    int k = i - 245760; ufb[k] = (__bf16)Ufb[k];
  } else {
    int k = i - 262144; uft[k] = (__bf16)Uft[k];
  }
}

__global__ void __launch_bounds__(128)
finalize_kernel(const __bf16* __restrict__ h_bu, const float* __restrict__ part,
                float* __restrict__ out)
{
  int b = blockIdx.x, ch = threadIdx.x;
  out[(size_t)b * 256 + ch] = (float)h_bu[((size_t)b * MPT) * HS + ch];
  const float* pp = part + (size_t)b * 512 + ch;   // 4 partials per tree
  out[(size_t)b * 256 + 128 + ch] = (pp[0] + pp[128] + pp[256] + pp[384]) * (1.0f / 256.0f);
}

extern "C" void kernel_launch(void* const* d_in, const int* in_sizes, int n_in,
                              void* d_out, int out_size, void* d_ws, size_t ws_size,
                              hipStream_t stream) {
  const float* X     = (const float*)d_in[0];
  const float* W_bu  = (const float*)d_in[3];
  const float* U_bu  = (const float*)d_in[4];
  const float* b_bu  = (const float*)d_in[5];
  const float* Uf_bu = (const float*)d_in[6];
  const float* bf_bu = (const float*)d_in[7];
  const float* W_td  = (const float*)d_in[8];
  const float* U_td  = (const float*)d_in[9];
  const float* b_td  = (const float*)d_in[10];
  const float* Uf_td = (const float*)d_in[11];
  const float* bf_td = (const float*)d_in[12];

  char* p = (char*)d_ws;
  __bf16* wbu  = (__bf16*)p; p += (size_t)384 * 256 * 2;
  __bf16* wtd  = (__bf16*)p; p += (size_t)384 * 384 * 2;
  __bf16* ufb  = (__bf16*)p; p += (size_t)128 * 128 * 2;
  __bf16* uft  = (__bf16*)p; p += (size_t)128 * 128 * 2;
  __bf16* h_bu = (__bf16*)p; p += (size_t)NNODE * HS * 2;
  __bf16* h_td = (__bf16*)p; p += (size_t)NNODE * HS * 2;
  float*  cws  = (float*)p;  p += (size_t)NNODE * HS * 4;
  float*  part = (float*)p;  // 1024 * 128 f32

  prep<<<1088, 256, 0, stream>>>(W_bu, U_bu, W_td, U_td, Uf_bu, Uf_td, wbu, wtd, ufb, uft);

  // bottom-up: merged t8+t7, then internal t6, t5
  bu_bottom<<<1024, 512, 0, stream>>>(X, wbu, b_bu, ufb, bf_bu, h_bu, cws);
  level_big<1><<<256, 256, 0, stream>>>(6, X, wbu, b_bu, ufb, bf_bu, h_bu, h_td, cws);
  level_big<1><<<128, 256, 0, stream>>>(5, X, wbu, b_bu, ufb, bf_bu, h_bu, h_td, cws);

  // merged small levels: BU t=4..0 + TD t=0..4
  small_both<<<256, 512, 0, stream>>>(X, wbu, b_bu, ufb, bf_bu,
                                      wtd, b_td, uft, bf_td, h_bu, h_td, cws);

  // top-down: t5, t6, then merged t7+t8 (leaf-mean output)
  level_big<3><<<128, 256, 0, stream>>>(5, X, wtd, b_td, uft, bf_td, h_bu, h_td, cws);
  level_big<3><<<256, 256, 0, stream>>>(6, X, wtd, b_td, uft, bf_td, h_bu, h_td, cws);
  td_bottom<<<1024, 512, 0, stream>>>(X, wtd, b_td, uft, bf_td, h_bu, h_td, cws, part);

  finalize_kernel<<<256, 128, 0, stream>>>(h_bu, part, (float*)d_out);
}